// Round 3
// baseline (447.668 us; speedup 1.0000x reference)
//
#include <hip/hip_runtime.h>

typedef __bf16 bfrag __attribute__((ext_vector_type(8)));
typedef float f32x4 __attribute__((ext_vector_type(4)));
typedef unsigned short us8 __attribute__((ext_vector_type(8)));

__device__ __forceinline__ float bf2f(unsigned short s) {
  unsigned u = ((unsigned)s) << 16;
  float f;
  __builtin_memcpy(&f, &u, 4);
  return f;
}
__device__ __forceinline__ unsigned short f2bf(float f) {
  unsigned u;
  __builtin_memcpy(&u, &f, 4);
  u += 0x7fffu + ((u >> 16) & 1u);
  return (unsigned short)(u >> 16);
}
// read element i of a float array whose storage is f32 (isf=1) or bf16 (isf=0)
__device__ __forceinline__ float rdf(const void* p, size_t i, int isf) {
  return isf ? ((const float*)p)[i] : bf2f(((const unsigned short*)p)[i]);
}

// ---------------- input dtype detector ---------------------------------
// Even-index 16-bit words of x: bf16 world -> sane exponents; f32 world ->
// those words are mantissa bits -> ~47% crazy exponent patterns.
__global__ __launch_bounds__(256) void detect_k(
    const unsigned short* __restrict__ x, int* __restrict__ flag) {
  __shared__ int cnt;
  if (threadIdx.x == 0) cnt = 0;
  __syncthreads();
  int c = 0;
  for (int i = threadIdx.x; i < 4096; i += 256) {
    unsigned short s = x[2 * i];
    int e = (s >> 7) & 0xFF;
    if (e > 0xC2 || (e != 0 && e < 0x3D)) c++;
  }
  atomicAdd(&cnt, c);
  __syncthreads();
  if (threadIdx.x == 0) flag[0] = (cnt > 256) ? 1 : 0;
}

// ---------------- weight transpose: W[K][N] -> Wt[N][K] (bf16 out) ------
__global__ __launch_bounds__(256) void transpose_k(
    const void* __restrict__ W, unsigned short* __restrict__ Wt,
    int K, int N, const int* __restrict__ flag) {
  __shared__ unsigned short tile[32][33];
  int isf = flag[0];
  int tid = threadIdx.x;
  int n0 = blockIdx.x * 32, k0 = blockIdx.y * 32;
#pragma unroll
  for (int i = 0; i < 4; i++) {
    int e = tid + i * 256;
    int r = e >> 5, c = e & 31;
    tile[r][c] = f2bf(rdf(W, (size_t)(k0 + r) * N + n0 + c, isf));
  }
  __syncthreads();
#pragma unroll
  for (int i = 0; i < 4; i++) {
    int e = tid + i * 256;
    int r = e >> 5, c = e & 31;
    Wt[(size_t)(n0 + r) * K + k0 + c] = tile[c][r];
  }
}

// ---------------- layernorm (torch-style: ddof=1 std, eps on std) ------
// one wave per token, E=512 = 64 lanes * 8 elems
// XMODE 0: x dtype per flag (external input). XMODE 1: x always f32 (internal).
template <int XMODE>
__global__ __launch_bounds__(256) void norm_k(
    const void* __restrict__ xin,
    const void* __restrict__ alpha,
    const void* __restrict__ beta,
    unsigned short* __restrict__ out,
    const int* __restrict__ flag) {
  constexpr int E = 512;
  int isf = flag[0];
  int xf = XMODE ? 1 : isf;
  int tid = threadIdx.x;
  int wave = tid >> 6, lane = tid & 63;
  size_t tok = (size_t)blockIdx.x * 4 + wave;
  float v[8];
  if (xf) {
    const float* xp = (const float*)xin + tok * E + lane * 8;
    float4 a0 = *(const float4*)xp;
    float4 a1 = *(const float4*)(xp + 4);
    v[0] = a0.x; v[1] = a0.y; v[2] = a0.z; v[3] = a0.w;
    v[4] = a1.x; v[5] = a1.y; v[6] = a1.z; v[7] = a1.w;
  } else {
    us8 u = *(const us8*)((const unsigned short*)xin + tok * E + lane * 8);
#pragma unroll
    for (int j = 0; j < 8; j++) v[j] = bf2f(u[j]);
  }
  float s = 0.f, sq = 0.f;
#pragma unroll
  for (int j = 0; j < 8; j++) { s += v[j]; sq += v[j] * v[j]; }
#pragma unroll
  for (int off = 1; off < 64; off <<= 1) {
    s += __shfl_xor(s, off, 64);
    sq += __shfl_xor(sq, off, 64);
  }
  float mean = s * (1.0f / 512.0f);
  float var = fmaxf((sq - 512.0f * mean * mean) * (1.0f / 511.0f), 0.0f);
  float inv = rdf(alpha, 0, isf) / (sqrtf(var) + 1e-6f);
  float be = rdf(beta, 0, isf);
  us8 ov;
#pragma unroll
  for (int j = 0; j < 8; j++) ov[j] = f2bf((v[j] - mean) * inv + be);
  *(us8*)((unsigned short*)out + tok * E + lane * 8) = ov;
}

// ---------------- GEMM: out[M,N] = act(A[M,K] @ Bt[N,K]^T + bias) + res --
// A, Bt always bf16 (internal). bias dtype per flag.
// RES: 0 none, 1 external residual (dtype per flag), 2 f32 internal residual.
// OUTM: 0 bf16 always (internal), 1 f32 always (internal), 2 per-flag (d_out).
template <int RES, int OUTM, int RELU>
__global__ __launch_bounds__(256) void gemm_k(
    const unsigned short* __restrict__ A,
    const unsigned short* __restrict__ Bt,
    const void* __restrict__ bias,
    const void* __restrict__ res,
    void* __restrict__ outp,
    int N, int K, const int* __restrict__ flag) {
  __shared__ alignas(16) unsigned short As[64][40];
  __shared__ alignas(16) unsigned short Bs[64][40];
  int isf = flag[0];
  int outf32 = (OUTM == 1) || (OUTM == 2 && isf);
  int tid = threadIdx.x;
  int wave = tid >> 6, lane = tid & 63, quad = lane >> 4, l16 = lane & 15;
  size_t m0 = (size_t)blockIdx.x * 64;
  size_t n0 = (size_t)blockIdx.y * 64;
  int srow = tid >> 2;
  int sseg = (tid & 3) * 8;

  f32x4 acc[4] = {{0, 0, 0, 0}, {0, 0, 0, 0}, {0, 0, 0, 0}, {0, 0, 0, 0}};
  const unsigned short* ap = A + (m0 + srow) * K + sseg;
  const unsigned short* bp = Bt + (n0 + srow) * K + sseg;

  for (int k0 = 0; k0 < K; k0 += 32) {
    __syncthreads();
    *(uint4*)&As[srow][sseg] = *(const uint4*)(ap + k0);
    *(uint4*)&Bs[srow][sseg] = *(const uint4*)(bp + k0);
    __syncthreads();
    bfrag af = *(const bfrag*)&As[wave * 16 + l16][quad * 8];
#pragma unroll
    for (int nt = 0; nt < 4; nt++) {
      bfrag bf = *(const bfrag*)&Bs[nt * 16 + l16][quad * 8];
      acc[nt] = __builtin_amdgcn_mfma_f32_16x16x32_bf16(af, bf, acc[nt], 0, 0, 0);
    }
  }
#pragma unroll
  for (int nt = 0; nt < 4; nt++) {
    size_t n = n0 + nt * 16 + l16;
    float bv = rdf(bias, n, isf);
#pragma unroll
    for (int r = 0; r < 4; r++) {
      size_t m = m0 + wave * 16 + quad * 4 + r;
      float vv = acc[nt][r] + bv;
      if (RELU) vv = fmaxf(vv, 0.0f);
      if (RES == 1) vv += rdf(res, m * N + n, isf);
      else if (RES == 2) vv += ((const float*)res)[m * N + n];
      if (outf32) ((float*)outp)[m * N + n] = vv;
      else ((unsigned short*)outp)[m * N + n] = f2bf(vv);
    }
  }
}

// ---------------- flash attention --------------------------------------
// block: one (b,h), 64 queries (16/wave). K-tiles of 64 keys.
__global__ __launch_bounds__(256) void attn_k(
    const unsigned short* __restrict__ Q,
    const unsigned short* __restrict__ Kg,
    const unsigned short* __restrict__ Vg,
    const int* __restrict__ mask,
    unsigned short* __restrict__ ctx) {
  constexpr int S = 2048, E = 512, DH = 64;
  __shared__ alignas(16) unsigned short Kt[64][72];
  __shared__ alignas(16) unsigned short Vt[64][72];  // transposed: Vt[d][key]
  __shared__ alignas(16) unsigned short Pl[4][16][72];
  __shared__ int msk[64];
  int tid = threadIdx.x, wave = tid >> 6, lane = tid & 63;
  int quad = lane >> 4, l16 = lane & 15;
  int q0 = blockIdx.x * 64;
  int b = blockIdx.y >> 3, h = blockIdx.y & 7;
  const size_t rowbase = (size_t)b * S;

  bfrag qf0, qf1;
  {
    size_t qrow = rowbase + q0 + wave * 16 + l16;
    const unsigned short* qp = Q + qrow * E + h * DH + quad * 8;
    qf0 = *(const bfrag*)qp;
    qf1 = *(const bfrag*)(qp + 32);
  }
  float m_i[4] = {-1e9f, -1e9f, -1e9f, -1e9f};
  float l_i[4] = {0.f, 0.f, 0.f, 0.f};
  f32x4 o[4] = {{0, 0, 0, 0}, {0, 0, 0, 0}, {0, 0, 0, 0}, {0, 0, 0, 0}};

  int srow = tid >> 3;
  int sseg = (tid & 7) * 8;

  for (int kt = 0; kt < S; kt += 64) {
    __syncthreads();
#pragma unroll
    for (int half = 0; half < 2; half++) {
      int row = srow + half * 32;
      const unsigned short* kp = Kg + (rowbase + kt + row) * E + h * DH + sseg;
      *(uint4*)&Kt[row][sseg] = *(const uint4*)kp;
      us8 vv = *(const us8*)(Vg + (rowbase + kt + row) * E + h * DH + sseg);
#pragma unroll
      for (int j = 0; j < 8; j++) Vt[sseg + j][row] = vv[j];
    }
    if (tid < 64) msk[tid] = mask[rowbase + kt + tid];
    __syncthreads();

    float sc[4][4];
#pragma unroll
    for (int nt = 0; nt < 4; nt++) {
      f32x4 s = {0, 0, 0, 0};
      bfrag k0f = *(const bfrag*)&Kt[nt * 16 + l16][quad * 8];
      bfrag k1f = *(const bfrag*)&Kt[nt * 16 + l16][32 + quad * 8];
      s = __builtin_amdgcn_mfma_f32_16x16x32_bf16(qf0, k0f, s, 0, 0, 0);
      s = __builtin_amdgcn_mfma_f32_16x16x32_bf16(qf1, k1f, s, 0, 0, 0);
      int mv = msk[nt * 16 + l16];
#pragma unroll
      for (int r = 0; r < 4; r++) {
        float x = s[r] * 0.125f;  // 1/sqrt(64)
        sc[nt][r] = (mv == 0) ? -1e9f : x;
      }
    }
#pragma unroll
    for (int r = 0; r < 4; r++) {
      float mx = fmaxf(fmaxf(sc[0][r], sc[1][r]), fmaxf(sc[2][r], sc[3][r]));
#pragma unroll
      for (int off = 1; off < 16; off <<= 1) mx = fmaxf(mx, __shfl_xor(mx, off, 64));
      float mnew = fmaxf(m_i[r], mx);
      float al = __expf(fminf(m_i[r] - mnew, 0.0f));
      m_i[r] = mnew;
      float rs = 0.0f;
#pragma unroll
      for (int nt = 0; nt < 4; nt++) {
        float p = __expf(fminf(sc[nt][r] - mnew, 0.0f));
        rs += p;
        Pl[wave][quad * 4 + r][nt * 16 + l16] = f2bf(p);
      }
#pragma unroll
      for (int off = 1; off < 16; off <<= 1) rs += __shfl_xor(rs, off, 64);
      l_i[r] = l_i[r] * al + rs;
#pragma unroll
      for (int dt = 0; dt < 4; dt++) o[dt][r] *= al;
    }
    __syncthreads();
    bfrag pa0 = *(const bfrag*)&Pl[wave][l16][quad * 8];
    bfrag pa1 = *(const bfrag*)&Pl[wave][l16][32 + quad * 8];
#pragma unroll
    for (int dt = 0; dt < 4; dt++) {
      bfrag vb0 = *(const bfrag*)&Vt[dt * 16 + l16][quad * 8];
      bfrag vb1 = *(const bfrag*)&Vt[dt * 16 + l16][32 + quad * 8];
      o[dt] = __builtin_amdgcn_mfma_f32_16x16x32_bf16(pa0, vb0, o[dt], 0, 0, 0);
      o[dt] = __builtin_amdgcn_mfma_f32_16x16x32_bf16(pa1, vb1, o[dt], 0, 0, 0);
    }
  }
#pragma unroll
  for (int dt = 0; dt < 4; dt++) {
#pragma unroll
    for (int r = 0; r < 4; r++) {
      size_t qrow = rowbase + q0 + wave * 16 + quad * 4 + r;
      float linv = 1.0f / fmaxf(l_i[r], 1e-30f);
      ctx[qrow * E + h * DH + dt * 16 + l16] = f2bf(o[dt][r] * linv);
    }
  }
}

extern "C" void kernel_launch(void* const* d_in, const int* in_sizes, int n_in,
                              void* d_out, int out_size, void* d_ws, size_t ws_size,
                              hipStream_t stream) {
  const unsigned short* x  = (const unsigned short*)d_in[0];
  const int* mask          = (const int*)d_in[1];
  const void* wq = d_in[2];  const void* bq = d_in[3];
  const void* wk = d_in[4];  const void* bk = d_in[5];
  const void* wv = d_in[6];  const void* bv = d_in[7];
  const void* wo = d_in[8];  const void* bo = d_in[9];
  const void* w1 = d_in[10]; const void* b1 = d_in[11];
  const void* w2 = d_in[12]; const void* b2 = d_in[13];
  const void* alpha1 = d_in[14]; const void* beta1 = d_in[15];
  const void* alpha2 = d_in[16]; const void* beta2 = d_in[17];

  // workspace layout (bytes); total ~62.1 MB with overlays
  char* ws = (char*)d_ws;
  int* flag           = (int*)(ws + 0);
  unsigned short* wqT = (unsigned short*)(ws + 65536);
  unsigned short* wkT = (unsigned short*)(ws + 589824);
  unsigned short* wvT = (unsigned short*)(ws + 1114112);
  unsigned short* woT = (unsigned short*)(ws + 1638400);
  unsigned short* w1T = (unsigned short*)(ws + 2162688);   // [2048][512] 2MB
  unsigned short* w2T = (unsigned short*)(ws + 4259840);   // [512][2048] 2MB
  float*          x1  = (float*)         (ws + 6356992);   // [8192,512] f32 16MB
  unsigned short* n1  = (unsigned short*)(ws + 23134208);  // 8MB (also ctx, n2)
  unsigned short* ctx = n1;
  unsigned short* n2  = n1;
  unsigned short* qb  = (unsigned short*)(ws + 31522816);  // 8MB (ff1 starts here)
  unsigned short* kb  = (unsigned short*)(ws + 39911424);  // 8MB
  unsigned short* vb  = (unsigned short*)(ws + 48300032);  // 8MB
  unsigned short* ff1 = qb;                                // [8192,2048] 32MB

  dim3 blk(256);

  detect_k<<<1, blk, 0, stream>>>(x, flag);

  // weight transposes (always emit bf16)
  transpose_k<<<dim3(16, 16), blk, 0, stream>>>(wq, wqT, 512, 512, flag);
  transpose_k<<<dim3(16, 16), blk, 0, stream>>>(wk, wkT, 512, 512, flag);
  transpose_k<<<dim3(16, 16), blk, 0, stream>>>(wv, wvT, 512, 512, flag);
  transpose_k<<<dim3(16, 16), blk, 0, stream>>>(wo, woT, 512, 512, flag);
  transpose_k<<<dim3(64, 16), blk, 0, stream>>>(w1, w1T, 512, 2048, flag);
  transpose_k<<<dim3(16, 64), blk, 0, stream>>>(w2, w2T, 2048, 512, flag);

  // norm1 (x dtype per flag)
  norm_k<0><<<2048, blk, 0, stream>>>(x, alpha1, beta1, n1, flag);
  // QKV projections
  gemm_k<0, 0, 0><<<dim3(128, 8), blk, 0, stream>>>(n1, wqT, bq, nullptr, qb, 512, 512, flag);
  gemm_k<0, 0, 0><<<dim3(128, 8), blk, 0, stream>>>(n1, wkT, bk, nullptr, kb, 512, 512, flag);
  gemm_k<0, 0, 0><<<dim3(128, 8), blk, 0, stream>>>(n1, wvT, bv, nullptr, vb, 512, 512, flag);
  // attention (ctx overwrites n1 slot — n1 dead after QKV)
  attn_k<<<dim3(32, 32), blk, 0, stream>>>(qb, kb, vb, mask, ctx);
  // out projection + residual(x, dtype per flag) -> x1 (fp32)
  gemm_k<1, 1, 0><<<dim3(128, 8), blk, 0, stream>>>(ctx, woT, bo, (const void*)x, x1, 512, 512, flag);
  // norm2 (x1 internal f32)
  norm_k<1><<<2048, blk, 0, stream>>>(x1, alpha2, beta2, n2, flag);
  // ffn1 with relu -> ff1
  gemm_k<0, 0, 1><<<dim3(128, 32), blk, 0, stream>>>(n2, w1T, b1, nullptr, ff1, 2048, 512, flag);
  // ffn2 + residual(x1 f32) -> d_out (dtype per flag: f32 in f32 world)
  gemm_k<2, 2, 0><<<dim3(128, 8), blk, 0, stream>>>(ff1, w2T, b2, x1, d_out, 512, 2048, flag);
}

// Round 4
// 360.975 us; speedup vs baseline: 1.2402x; 1.2402x over previous
//
#include <hip/hip_runtime.h>

typedef __bf16 bfrag __attribute__((ext_vector_type(8)));
typedef float f32x4 __attribute__((ext_vector_type(4)));
typedef unsigned short us8 __attribute__((ext_vector_type(8)));

__device__ __forceinline__ float bf2f(unsigned short s) {
  unsigned u = ((unsigned)s) << 16;
  float f;
  __builtin_memcpy(&f, &u, 4);
  return f;
}
__device__ __forceinline__ unsigned short f2bf(float f) {
  unsigned u;
  __builtin_memcpy(&u, &f, 4);
  u += 0x7fffu + ((u >> 16) & 1u);
  return (unsigned short)(u >> 16);
}
__device__ __forceinline__ float rdf(const void* p, size_t i, int isf) {
  return isf ? ((const float*)p)[i] : bf2f(((const unsigned short*)p)[i]);
}

// ---------------- input dtype detector ---------------------------------
__global__ __launch_bounds__(256) void detect_k(
    const unsigned short* __restrict__ x, int* __restrict__ flag) {
  __shared__ int cnt;
  if (threadIdx.x == 0) cnt = 0;
  __syncthreads();
  int c = 0;
  for (int i = threadIdx.x; i < 4096; i += 256) {
    unsigned short s = x[2 * i];
    int e = (s >> 7) & 0xFF;
    if (e > 0xC2 || (e != 0 && e < 0x3D)) c++;
  }
  atomicAdd(&cnt, c);
  __syncthreads();
  if (threadIdx.x == 0) flag[0] = (cnt > 256) ? 1 : 0;
}

// ---------------- weight transpose: W[K][N] -> Wt[N][K] (bf16 out) ------
__global__ __launch_bounds__(256) void transpose_k(
    const void* __restrict__ W, unsigned short* __restrict__ Wt,
    int K, int N, const int* __restrict__ flag) {
  __shared__ unsigned short tile[32][33];
  int isf = flag[0];
  int tid = threadIdx.x;
  int n0 = blockIdx.x * 32, k0 = blockIdx.y * 32;
#pragma unroll
  for (int i = 0; i < 4; i++) {
    int e = tid + i * 256;
    int r = e >> 5, c = e & 31;
    tile[r][c] = f2bf(rdf(W, (size_t)(k0 + r) * N + n0 + c, isf));
  }
  __syncthreads();
#pragma unroll
  for (int i = 0; i < 4; i++) {
    int e = tid + i * 256;
    int r = e >> 5, c = e & 31;
    Wt[(size_t)(n0 + r) * K + k0 + c] = tile[c][r];
  }
}

// ---------------- bias concat -> f32 [bq|bk|bv|bo|b1|b2] = 4608 ---------
__global__ __launch_bounds__(256) void bcat_k(
    const void* bq, const void* bk, const void* bv, const void* bo,
    const void* b1, const void* b2, float* __restrict__ bcat,
    const int* __restrict__ flag) {
  int isf = flag[0];
  int i = blockIdx.x * 256 + threadIdx.x;
  if (i >= 4608) return;
  float v;
  if (i < 512) v = rdf(bq, i, isf);
  else if (i < 1024) v = rdf(bk, i - 512, isf);
  else if (i < 1536) v = rdf(bv, i - 1024, isf);
  else if (i < 2048) v = rdf(bo, i - 1536, isf);
  else if (i < 4096) v = rdf(b1, i - 2048, isf);
  else v = rdf(b2, i - 4096, isf);
  bcat[i] = v;
}

// ---------------- V transpose: qkb v-cols -> vbt[bh][d][s] --------------
__global__ __launch_bounds__(256) void vtrans_k(
    const unsigned short* __restrict__ qkb, unsigned short* __restrict__ vbt) {
  __shared__ unsigned short tile[32][33];
  int tid = threadIdx.x;
  int s0 = blockIdx.x * 32;
  int d0 = blockIdx.y * 32;
  int bh = blockIdx.z, b = bh >> 3, h = bh & 7;
#pragma unroll
  for (int i = 0; i < 4; i++) {
    int e = tid + i * 256;
    int r = e >> 5, c = e & 31;
    tile[r][c] = qkb[((size_t)b * 2048 + s0 + r) * 1536 + 1024 + h * 64 + d0 + c];
  }
  __syncthreads();
#pragma unroll
  for (int i = 0; i < 4; i++) {
    int e = tid + i * 256;
    int r = e >> 5, c = e & 31;
    vbt[((size_t)bh * 64 + d0 + r) * 2048 + s0 + c] = tile[c][r];
  }
}

// ---------------- layernorm (ddof=1 std, eps on std) --------------------
template <int XMODE>
__global__ __launch_bounds__(256) void norm_k(
    const void* __restrict__ xin, const void* __restrict__ alpha,
    const void* __restrict__ beta, unsigned short* __restrict__ out,
    const int* __restrict__ flag) {
  constexpr int E = 512;
  int isf = flag[0];
  int xf = XMODE ? 1 : isf;
  int tid = threadIdx.x;
  int wave = tid >> 6, lane = tid & 63;
  size_t tok = (size_t)blockIdx.x * 4 + wave;
  float v[8];
  if (xf) {
    const float* xp = (const float*)xin + tok * E + lane * 8;
    float4 a0 = *(const float4*)xp;
    float4 a1 = *(const float4*)(xp + 4);
    v[0] = a0.x; v[1] = a0.y; v[2] = a0.z; v[3] = a0.w;
    v[4] = a1.x; v[5] = a1.y; v[6] = a1.z; v[7] = a1.w;
  } else {
    us8 u = *(const us8*)((const unsigned short*)xin + tok * E + lane * 8);
#pragma unroll
    for (int j = 0; j < 8; j++) v[j] = bf2f(u[j]);
  }
  float s = 0.f, sq = 0.f;
#pragma unroll
  for (int j = 0; j < 8; j++) { s += v[j]; sq += v[j] * v[j]; }
#pragma unroll
  for (int off = 1; off < 64; off <<= 1) {
    s += __shfl_xor(s, off, 64);
    sq += __shfl_xor(sq, off, 64);
  }
  float mean = s * (1.0f / 512.0f);
  float var = fmaxf((sq - 512.0f * mean * mean) * (1.0f / 511.0f), 0.0f);
  float inv = rdf(alpha, 0, isf) / (sqrtf(var) + 1e-6f);
  float be = rdf(beta, 0, isf);
  us8 ov;
#pragma unroll
  for (int j = 0; j < 8; j++) ov[j] = f2bf((v[j] - mean) * inv + be);
  *(us8*)((unsigned short*)out + tok * E + lane * 8) = ov;
}

// ---------------- GEMM 64x64 tile, BK=64 --------------------------------
// out[M,N] = act(A[M,K] @ Bt[N,K]^T + bias) + res. bias always f32.
// RES: 0 none, 1 external (dtype per flag), 2 f32 internal.
// OUTM: 0 bf16, 1 f32, 2 per-flag (d_out).
template <int RES, int OUTM, int RELU>
__global__ __launch_bounds__(256) void gemm_k(
    const unsigned short* __restrict__ A,
    const unsigned short* __restrict__ Bt,
    const float* __restrict__ bias,
    const void* __restrict__ res,
    void* __restrict__ outp,
    int N, int K, const int* __restrict__ flag) {
  __shared__ alignas(16) unsigned short As[64][72];
  __shared__ alignas(16) unsigned short Bs[64][72];
  int isf = flag[0];
  int outf32 = (OUTM == 1) || (OUTM == 2 && isf);
  int tid = threadIdx.x;
  int wave = tid >> 6, lane = tid & 63, quad = lane >> 4, l16 = lane & 15;
  size_t m0 = (size_t)blockIdx.x * 64;
  size_t n0 = (size_t)blockIdx.y * 64;
  int srow = tid >> 2;
  int c0 = (tid & 3) * 8;

  f32x4 acc[4] = {{0, 0, 0, 0}, {0, 0, 0, 0}, {0, 0, 0, 0}, {0, 0, 0, 0}};
  const unsigned short* ap = A + (m0 + srow) * K + c0;
  const unsigned short* bp = Bt + (n0 + srow) * K + c0;

  for (int k0 = 0; k0 < K; k0 += 64) {
    __syncthreads();
    *(uint4*)&As[srow][c0]      = *(const uint4*)(ap + k0);
    *(uint4*)&As[srow][c0 + 32] = *(const uint4*)(ap + k0 + 32);
    *(uint4*)&Bs[srow][c0]      = *(const uint4*)(bp + k0);
    *(uint4*)&Bs[srow][c0 + 32] = *(const uint4*)(bp + k0 + 32);
    __syncthreads();
    bfrag af0 = *(const bfrag*)&As[wave * 16 + l16][quad * 8];
    bfrag af1 = *(const bfrag*)&As[wave * 16 + l16][32 + quad * 8];
#pragma unroll
    for (int nt = 0; nt < 4; nt++) {
      bfrag b0 = *(const bfrag*)&Bs[nt * 16 + l16][quad * 8];
      bfrag b1 = *(const bfrag*)&Bs[nt * 16 + l16][32 + quad * 8];
      acc[nt] = __builtin_amdgcn_mfma_f32_16x16x32_bf16(af0, b0, acc[nt], 0, 0, 0);
      acc[nt] = __builtin_amdgcn_mfma_f32_16x16x32_bf16(af1, b1, acc[nt], 0, 0, 0);
    }
  }
#pragma unroll
  for (int nt = 0; nt < 4; nt++) {
    size_t n = n0 + nt * 16 + l16;
    float bv = bias[n];
#pragma unroll
    for (int r = 0; r < 4; r++) {
      size_t m = m0 + wave * 16 + quad * 4 + r;
      float vv = acc[nt][r] + bv;
      if (RELU) vv = fmaxf(vv, 0.0f);
      if (RES == 1) vv += rdf(res, m * N + n, isf);
      else if (RES == 2) vv += ((const float*)res)[m * N + n];
      if (outf32) ((float*)outp)[m * N + n] = vv;
      else ((unsigned short*)outp)[m * N + n] = f2bf(vv);
    }
  }
}

// ---------------- flash attention (max-free softmax) --------------------
// block: one (b,h) x 64 queries. K-tiles of 64. V pre-transposed in vbt.
__global__ __launch_bounds__(256) void attn_k(
    const unsigned short* __restrict__ qkb,  // [8192][1536] q|k|v
    const unsigned short* __restrict__ vbt,  // [32*64][2048] = V^T per bh
    const int* __restrict__ mask,
    unsigned short* __restrict__ ctx) {      // [8192][512]
  constexpr int S = 2048;
  __shared__ alignas(16) unsigned short Kt[64][72];
  __shared__ alignas(16) unsigned short Vt[64][72];  // [d][key]
  __shared__ alignas(16) unsigned short Pl[4][16][72];
  __shared__ int msk[64];
  int tid = threadIdx.x, wave = tid >> 6, lane = tid & 63;
  int quad = lane >> 4, l16 = lane & 15;
  int q0 = blockIdx.x * 64;
  int bh = blockIdx.y, b = bh >> 3, h = bh & 7;
  size_t rowbase = (size_t)b * S;

  bfrag qf0, qf1;
  {
    const unsigned short* qp =
        qkb + (rowbase + q0 + wave * 16 + l16) * 1536 + h * 64 + quad * 8;
    qf0 = *(const bfrag*)qp;
    qf1 = *(const bfrag*)(qp + 32);
  }
  f32x4 o[4] = {{0, 0, 0, 0}, {0, 0, 0, 0}, {0, 0, 0, 0}, {0, 0, 0, 0}};
  float l_i[4] = {0.f, 0.f, 0.f, 0.f};

  int srow = tid >> 2;        // 0..63
  int c0 = (tid & 3) * 8;     // 0,8,16,24
  const unsigned short* kbase = qkb + 512 + h * 64;
  const unsigned short* vrow = vbt + ((size_t)bh * 64 + srow) * S;

  for (int kt = 0; kt < S; kt += 64) {
    __syncthreads();
    {
      const unsigned short* kp = kbase + (rowbase + kt + srow) * 1536;
      *(uint4*)&Kt[srow][c0]      = *(const uint4*)(kp + c0);
      *(uint4*)&Kt[srow][c0 + 32] = *(const uint4*)(kp + c0 + 32);
      *(uint4*)&Vt[srow][c0]      = *(const uint4*)(vrow + kt + c0);
      *(uint4*)&Vt[srow][c0 + 32] = *(const uint4*)(vrow + kt + c0 + 32);
    }
    if (tid < 64) msk[tid] = mask[rowbase + kt + tid];
    __syncthreads();

    float pr[4][4];
#pragma unroll
    for (int nt = 0; nt < 4; nt++) {
      f32x4 s = {0, 0, 0, 0};
      bfrag k0f = *(const bfrag*)&Kt[nt * 16 + l16][quad * 8];
      bfrag k1f = *(const bfrag*)&Kt[nt * 16 + l16][32 + quad * 8];
      s = __builtin_amdgcn_mfma_f32_16x16x32_bf16(qf0, k0f, s, 0, 0, 0);
      s = __builtin_amdgcn_mfma_f32_16x16x32_bf16(qf1, k1f, s, 0, 0, 0);
      int mv = msk[nt * 16 + l16];
#pragma unroll
      for (int r = 0; r < 4; r++) {
        float p = __expf(fminf(s[r] * 0.125f, 30.0f));  // scores bounded; clamp for safety
        pr[nt][r] = mv ? p : 0.0f;
      }
    }
#pragma unroll
    for (int r = 0; r < 4; r++) {
      l_i[r] += (pr[0][r] + pr[1][r]) + (pr[2][r] + pr[3][r]);
#pragma unroll
      for (int nt = 0; nt < 4; nt++)
        Pl[wave][quad * 4 + r][nt * 16 + l16] = f2bf(pr[nt][r]);
    }
    // Pl[wave] is wave-private; DS ops complete in order per wave -> no barrier
    bfrag pa0 = *(const bfrag*)&Pl[wave][l16][quad * 8];
    bfrag pa1 = *(const bfrag*)&Pl[wave][l16][32 + quad * 8];
#pragma unroll
    for (int dt = 0; dt < 4; dt++) {
      bfrag v0 = *(const bfrag*)&Vt[dt * 16 + l16][quad * 8];
      bfrag v1 = *(const bfrag*)&Vt[dt * 16 + l16][32 + quad * 8];
      o[dt] = __builtin_amdgcn_mfma_f32_16x16x32_bf16(pa0, v0, o[dt], 0, 0, 0);
      o[dt] = __builtin_amdgcn_mfma_f32_16x16x32_bf16(pa1, v1, o[dt], 0, 0, 0);
    }
  }
#pragma unroll
  for (int r = 0; r < 4; r++) {
#pragma unroll
    for (int off = 1; off < 16; off <<= 1) l_i[r] += __shfl_xor(l_i[r], off, 64);
    l_i[r] = 1.0f / fmaxf(l_i[r], 1e-30f);
  }
#pragma unroll
  for (int dt = 0; dt < 4; dt++) {
#pragma unroll
    for (int r = 0; r < 4; r++) {
      size_t qrow = rowbase + q0 + wave * 16 + quad * 4 + r;
      ctx[qrow * 512 + h * 64 + dt * 16 + l16] = f2bf(o[dt][r] * l_i[r]);
    }
  }
}

extern "C" void kernel_launch(void* const* d_in, const int* in_sizes, int n_in,
                              void* d_out, int out_size, void* d_ws, size_t ws_size,
                              hipStream_t stream) {
  const unsigned short* x = (const unsigned short*)d_in[0];
  const int* mask         = (const int*)d_in[1];
  const void* wq = d_in[2];  const void* bq = d_in[3];
  const void* wk = d_in[4];  const void* bk = d_in[5];
  const void* wv = d_in[6];  const void* bv = d_in[7];
  const void* wo = d_in[8];  const void* bo = d_in[9];
  const void* w1 = d_in[10]; const void* b1 = d_in[11];
  const void* w2 = d_in[12]; const void* b2 = d_in[13];
  const void* alpha1 = d_in[14]; const void* beta1 = d_in[15];
  const void* alpha2 = d_in[16]; const void* beta2 = d_in[17];

  // workspace layout (bytes); ~62.1 MB total with ff1 overlaying qkb+vbt
  char* ws = (char*)d_ws;
  int* flag            = (int*)(ws + 0);
  unsigned short* wqkvT= (unsigned short*)(ws + 65536);    // [1536][512] contiguous
  unsigned short* wqT  = wqkvT;
  unsigned short* wkT  = (unsigned short*)(ws + 589824);
  unsigned short* wvT  = (unsigned short*)(ws + 1114112);
  unsigned short* woT  = (unsigned short*)(ws + 1638400);
  unsigned short* w1T  = (unsigned short*)(ws + 2162688);  // [2048][512]
  unsigned short* w2T  = (unsigned short*)(ws + 4259840);  // [512][2048]
  float*          bcat = (float*)         (ws + 6356992);  // 4608 f32
  float*          x1   = (float*)         (ws + 6422528);  // [8192][512] f32
  unsigned short* n1   = (unsigned short*)(ws + 23199744); // also ctx, n2
  unsigned short* ctx  = n1;
  unsigned short* n2   = n1;
  unsigned short* qkb  = (unsigned short*)(ws + 31588352); // [8192][1536]
  unsigned short* vbt  = (unsigned short*)(ws + 56754176); // [2048][2048]
  unsigned short* ff1  = qkb;                              // [8192][2048] overlay

  dim3 blk(256);

  detect_k<<<1, blk, 0, stream>>>(x, flag);

  transpose_k<<<dim3(16, 16), blk, 0, stream>>>(wq, wqT, 512, 512, flag);
  transpose_k<<<dim3(16, 16), blk, 0, stream>>>(wk, wkT, 512, 512, flag);
  transpose_k<<<dim3(16, 16), blk, 0, stream>>>(wv, wvT, 512, 512, flag);
  transpose_k<<<dim3(16, 16), blk, 0, stream>>>(wo, woT, 512, 512, flag);
  transpose_k<<<dim3(64, 16), blk, 0, stream>>>(w1, w1T, 512, 2048, flag);
  transpose_k<<<dim3(16, 64), blk, 0, stream>>>(w2, w2T, 2048, 512, flag);
  bcat_k<<<18, blk, 0, stream>>>(bq, bk, bv, bo, b1, b2, bcat, flag);

  norm_k<0><<<2048, blk, 0, stream>>>(x, alpha1, beta1, n1, flag);
  // fused QKV projection: [8192][512] @ [1536][512]^T -> qkb
  gemm_k<0, 0, 0><<<dim3(128, 24), blk, 0, stream>>>(n1, wqkvT, bcat, nullptr, qkb, 1536, 512, flag);
  // pre-transpose V per (b,h): qkb v-cols -> vbt
  vtrans_k<<<dim3(64, 2, 32), blk, 0, stream>>>(qkb, vbt);
  // attention -> ctx (overwrites n1 slot)
  attn_k<<<dim3(32, 32), blk, 0, stream>>>(qkb, vbt, mask, ctx);
  // out projection + residual(x) -> x1 f32
  gemm_k<1, 1, 0><<<dim3(128, 8), blk, 0, stream>>>(ctx, woT, bcat + 1536, (const void*)x, x1, 512, 512, flag);
  norm_k<1><<<2048, blk, 0, stream>>>(x1, alpha2, beta2, n2, flag);
  // ffn1 + relu -> ff1 (overlays dead qkb/vbt)
  gemm_k<0, 0, 1><<<dim3(128, 32), blk, 0, stream>>>(n2, w1T, bcat + 2048, nullptr, ff1, 2048, 512, flag);
  // ffn2 + residual(x1) -> d_out (f32 in f32 world)
  gemm_k<2, 2, 0><<<dim3(128, 8), blk, 0, stream>>>(ff1, w2T, bcat + 4096, x1, d_out, 512, 2048, flag);
}

// Round 5
// 341.251 us; speedup vs baseline: 1.3118x; 1.0578x over previous
//
#include <hip/hip_runtime.h>

typedef __bf16 bfrag __attribute__((ext_vector_type(8)));
typedef float f32x4 __attribute__((ext_vector_type(4)));
typedef unsigned short us8 __attribute__((ext_vector_type(8)));

__device__ __forceinline__ float bf2f(unsigned short s) {
  unsigned u = ((unsigned)s) << 16;
  float f;
  __builtin_memcpy(&f, &u, 4);
  return f;
}
__device__ __forceinline__ unsigned short f2bf(float f) {
  unsigned u;
  __builtin_memcpy(&u, &f, 4);
  u += 0x7fffu + ((u >> 16) & 1u);
  return (unsigned short)(u >> 16);
}
__device__ __forceinline__ float rdf(const void* p, size_t i, int isf) {
  return isf ? ((const float*)p)[i] : bf2f(((const unsigned short*)p)[i]);
}
// async global->LDS, 16B per lane; LDS dest = wave-uniform base + lane*16
__device__ __forceinline__ void gld16(const unsigned short* g, unsigned short* l) {
  __builtin_amdgcn_global_load_lds(
      (const __attribute__((address_space(1))) unsigned int*)g,
      (__attribute__((address_space(3))) unsigned int*)l, 16, 0, 0);
}

// ---------------- input dtype detector ---------------------------------
__global__ __launch_bounds__(256) void detect_k(
    const unsigned short* __restrict__ x, int* __restrict__ flag) {
  __shared__ int cnt;
  if (threadIdx.x == 0) cnt = 0;
  __syncthreads();
  int c = 0;
  for (int i = threadIdx.x; i < 4096; i += 256) {
    unsigned short s = x[2 * i];
    int e = (s >> 7) & 0xFF;
    if (e > 0xC2 || (e != 0 && e < 0x3D)) c++;
  }
  atomicAdd(&cnt, c);
  __syncthreads();
  if (threadIdx.x == 0) flag[0] = (cnt > 256) ? 1 : 0;
}

// ---------------- weight transpose: W[K][N] -> Wt[N][K] (bf16 out) ------
__global__ __launch_bounds__(256) void transpose_k(
    const void* __restrict__ W, unsigned short* __restrict__ Wt,
    int K, int N, const int* __restrict__ flag) {
  __shared__ unsigned short tile[32][33];
  int isf = flag[0];
  int tid = threadIdx.x;
  int n0 = blockIdx.x * 32, k0 = blockIdx.y * 32;
#pragma unroll
  for (int i = 0; i < 4; i++) {
    int e = tid + i * 256;
    int r = e >> 5, c = e & 31;
    tile[r][c] = f2bf(rdf(W, (size_t)(k0 + r) * N + n0 + c, isf));
  }
  __syncthreads();
#pragma unroll
  for (int i = 0; i < 4; i++) {
    int e = tid + i * 256;
    int r = e >> 5, c = e & 31;
    Wt[(size_t)(n0 + r) * K + k0 + c] = tile[c][r];
  }
}

// ---------------- bias concat -> f32 [bq|bk|bv|bo|b1|b2] = 4608 ---------
__global__ __launch_bounds__(256) void bcat_k(
    const void* bq, const void* bk, const void* bv, const void* bo,
    const void* b1, const void* b2, float* __restrict__ bcat,
    const int* __restrict__ flag) {
  int isf = flag[0];
  int i = blockIdx.x * 256 + threadIdx.x;
  if (i >= 4608) return;
  float v;
  if (i < 512) v = rdf(bq, i, isf);
  else if (i < 1024) v = rdf(bk, i - 512, isf);
  else if (i < 1536) v = rdf(bv, i - 1024, isf);
  else if (i < 2048) v = rdf(bo, i - 1536, isf);
  else if (i < 4096) v = rdf(b1, i - 2048, isf);
  else v = rdf(b2, i - 4096, isf);
  bcat[i] = v;
}

// ---------------- V transpose: qkb v-cols -> vbt[bh][d][s] --------------
__global__ __launch_bounds__(256) void vtrans_k(
    const unsigned short* __restrict__ qkb, unsigned short* __restrict__ vbt) {
  __shared__ unsigned short tile[32][33];
  int tid = threadIdx.x;
  int s0 = blockIdx.x * 32;
  int d0 = blockIdx.y * 32;
  int bh = blockIdx.z, b = bh >> 3, h = bh & 7;
#pragma unroll
  for (int i = 0; i < 4; i++) {
    int e = tid + i * 256;
    int r = e >> 5, c = e & 31;
    tile[r][c] = qkb[((size_t)b * 2048 + s0 + r) * 1536 + 1024 + h * 64 + d0 + c];
  }
  __syncthreads();
#pragma unroll
  for (int i = 0; i < 4; i++) {
    int e = tid + i * 256;
    int r = e >> 5, c = e & 31;
    vbt[((size_t)bh * 64 + d0 + r) * 2048 + s0 + c] = tile[c][r];
  }
}

// ---------------- layernorm (ddof=1 std, eps on std) --------------------
template <int XMODE>
__global__ __launch_bounds__(256) void norm_k(
    const void* __restrict__ xin, const void* __restrict__ alpha,
    const void* __restrict__ beta, unsigned short* __restrict__ out,
    const int* __restrict__ flag) {
  constexpr int E = 512;
  int isf = flag[0];
  int xf = XMODE ? 1 : isf;
  int tid = threadIdx.x;
  int wave = tid >> 6, lane = tid & 63;
  size_t tok = (size_t)blockIdx.x * 4 + wave;
  float v[8];
  if (xf) {
    const float* xp = (const float*)xin + tok * E + lane * 8;
    float4 a0 = *(const float4*)xp;
    float4 a1 = *(const float4*)(xp + 4);
    v[0] = a0.x; v[1] = a0.y; v[2] = a0.z; v[3] = a0.w;
    v[4] = a1.x; v[5] = a1.y; v[6] = a1.z; v[7] = a1.w;
  } else {
    us8 u = *(const us8*)((const unsigned short*)xin + tok * E + lane * 8);
#pragma unroll
    for (int j = 0; j < 8; j++) v[j] = bf2f(u[j]);
  }
  float s = 0.f, sq = 0.f;
#pragma unroll
  for (int j = 0; j < 8; j++) { s += v[j]; sq += v[j] * v[j]; }
#pragma unroll
  for (int off = 1; off < 64; off <<= 1) {
    s += __shfl_xor(s, off, 64);
    sq += __shfl_xor(sq, off, 64);
  }
  float mean = s * (1.0f / 512.0f);
  float var = fmaxf((sq - 512.0f * mean * mean) * (1.0f / 511.0f), 0.0f);
  float inv = rdf(alpha, 0, isf) / (sqrtf(var) + 1e-6f);
  float be = rdf(beta, 0, isf);
  us8 ov;
#pragma unroll
  for (int j = 0; j < 8; j++) ov[j] = f2bf((v[j] - mean) * inv + be);
  *(us8*)((unsigned short*)out + tok * E + lane * 8) = ov;
}

// ---------------- GEMM m97-style: 128xTN tile, BK=32, global_load_lds ----
// out[M,N] = act(A[M,K] @ Bt[N,K]^T + bias) + res. bias f32.
// TN: 128 (2x2 waves, 4x4 accs) or 64 (4x1 waves, 2x4 accs).
// RES: 0 none, 1 external (dtype per flag), 2 f32. OUTM: 0 bf16, 1 f32, 2 per-flag.
template <int TN, int RES, int OUTM, int RELU>
__global__ __launch_bounds__(256) void gemm2_k(
    const unsigned short* __restrict__ A,
    const unsigned short* __restrict__ Bt,
    const float* __restrict__ bias,
    const void* __restrict__ res,
    void* __restrict__ outp,
    int N, int K, const int* __restrict__ flag) {
  constexpr int MT = (TN == 128) ? 4 : 2;  // 16-row m-tiles per wave
  __shared__ alignas(16) unsigned short As[128 * 32];  // [row][k], un-padded
  __shared__ alignas(16) unsigned short Bs[TN * 32];
  int isf = flag[0];
  int outf32 = (OUTM == 1) || (OUTM == 2 && isf);
  int tid = threadIdx.x;
  int wave = tid >> 6, lane = tid & 63;
  int quad = lane >> 4, l16 = lane & 15;
  int wm = (TN == 128) ? (wave >> 1) : wave;
  int wn = (TN == 128) ? (wave & 1) : 0;
  size_t m0 = (size_t)blockIdx.x * 128;
  size_t n0 = (size_t)blockIdx.y * TN;

  int lrow = lane >> 2;        // 0..15
  int kseg = (lane & 3) * 8;   // shorts

  const unsigned short* ag = A + (m0 + wave * 16 + lrow) * K + kseg;
  const unsigned short* bg = Bt + (n0 + wave * 16 + lrow) * K + kseg;
  unsigned short* asl = &As[(wave * 16) * 32];
  unsigned short* bsl = &Bs[(wave * 16) * 32];

  f32x4 acc[MT][4];
#pragma unroll
  for (int i = 0; i < MT; i++)
#pragma unroll
    for (int j = 0; j < 4; j++) acc[i][j] = {0.f, 0.f, 0.f, 0.f};

  for (int k0 = 0; k0 < K; k0 += 32) {
    __syncthreads();
    gld16(ag + k0, asl);
    gld16(ag + (size_t)64 * K + k0, asl + 64 * 32);
    gld16(bg + k0, bsl);
    if (TN == 128) gld16(bg + (size_t)64 * K + k0, bsl + 64 * 32);
    __syncthreads();
    bfrag af[MT], bf[4];
#pragma unroll
    for (int i = 0; i < MT; i++)
      af[i] = *(const bfrag*)&As[(wm * (MT * 16) + i * 16 + l16) * 32 + quad * 8];
#pragma unroll
    for (int j = 0; j < 4; j++)
      bf[j] = *(const bfrag*)&Bs[(wn * 64 + j * 16 + l16) * 32 + quad * 8];
#pragma unroll
    for (int i = 0; i < MT; i++)
#pragma unroll
      for (int j = 0; j < 4; j++)
        acc[i][j] = __builtin_amdgcn_mfma_f32_16x16x32_bf16(af[i], bf[j], acc[i][j], 0, 0, 0);
  }
#pragma unroll
  for (int j = 0; j < 4; j++) {
    size_t n = n0 + wn * 64 + j * 16 + l16;
    float bv = bias[n];
#pragma unroll
    for (int i = 0; i < MT; i++) {
#pragma unroll
      for (int r = 0; r < 4; r++) {
        size_t m = m0 + wm * (MT * 16) + i * 16 + quad * 4 + r;
        float vv = acc[i][j][r] + bv;
        if (RELU) vv = fmaxf(vv, 0.0f);
        if (RES == 1) vv += rdf(res, m * N + n, isf);
        else if (RES == 2) vv += ((const float*)res)[m * N + n];
        if (outf32) ((float*)outp)[m * N + n] = vv;
        else ((unsigned short*)outp)[m * N + n] = f2bf(vv);
      }
    }
  }
}

// ---------------- flash attention (max-free softmax) --------------------
__global__ __launch_bounds__(256) void attn_k(
    const unsigned short* __restrict__ qkb,  // [8192][1536] q|k|v
    const unsigned short* __restrict__ vbt,  // [32*64][2048] = V^T per bh
    const int* __restrict__ mask,
    unsigned short* __restrict__ ctx) {      // [8192][512]
  constexpr int S = 2048;
  __shared__ alignas(16) unsigned short Kt[64][72];
  __shared__ alignas(16) unsigned short Vt[64][72];  // [d][key]
  __shared__ alignas(16) unsigned short Pl[4][16][68]; // stride 68: conflict-free stores
  __shared__ int msk[64];
  int tid = threadIdx.x, wave = tid >> 6, lane = tid & 63;
  int quad = lane >> 4, l16 = lane & 15;
  int q0 = blockIdx.x * 64;
  int bh = blockIdx.y, b = bh >> 3, h = bh & 7;
  size_t rowbase = (size_t)b * S;

  bfrag qf0, qf1;
  {
    const unsigned short* qp =
        qkb + (rowbase + q0 + wave * 16 + l16) * 1536 + h * 64 + quad * 8;
    qf0 = *(const bfrag*)qp;
    qf1 = *(const bfrag*)(qp + 32);
  }
  f32x4 o[4] = {{0, 0, 0, 0}, {0, 0, 0, 0}, {0, 0, 0, 0}, {0, 0, 0, 0}};
  float l_i[4] = {0.f, 0.f, 0.f, 0.f};

  int srow = tid >> 2;
  int c0 = (tid & 3) * 8;
  const unsigned short* kbase = qkb + 512 + h * 64;
  const unsigned short* vrow = vbt + ((size_t)bh * 64 + srow) * S;

  for (int kt = 0; kt < S; kt += 64) {
    __syncthreads();
    {
      const unsigned short* kp = kbase + (rowbase + kt + srow) * 1536;
      *(uint4*)&Kt[srow][c0]      = *(const uint4*)(kp + c0);
      *(uint4*)&Kt[srow][c0 + 32] = *(const uint4*)(kp + c0 + 32);
      *(uint4*)&Vt[srow][c0]      = *(const uint4*)(vrow + kt + c0);
      *(uint4*)&Vt[srow][c0 + 32] = *(const uint4*)(vrow + kt + c0 + 32);
    }
    if (tid < 64) msk[tid] = mask[rowbase + kt + tid];
    __syncthreads();

    float pr[4][4];
#pragma unroll
    for (int nt = 0; nt < 4; nt++) {
      f32x4 s = {0, 0, 0, 0};
      bfrag k0f = *(const bfrag*)&Kt[nt * 16 + l16][quad * 8];
      bfrag k1f = *(const bfrag*)&Kt[nt * 16 + l16][32 + quad * 8];
      s = __builtin_amdgcn_mfma_f32_16x16x32_bf16(qf0, k0f, s, 0, 0, 0);
      s = __builtin_amdgcn_mfma_f32_16x16x32_bf16(qf1, k1f, s, 0, 0, 0);
      int mv = msk[nt * 16 + l16];
#pragma unroll
      for (int r = 0; r < 4; r++) {
        float p = __expf(fminf(s[r] * 0.125f, 30.0f));
        pr[nt][r] = mv ? p : 0.0f;
      }
    }
#pragma unroll
    for (int r = 0; r < 4; r++) {
      l_i[r] += (pr[0][r] + pr[1][r]) + (pr[2][r] + pr[3][r]);
#pragma unroll
      for (int nt = 0; nt < 4; nt++)
        Pl[wave][quad * 4 + r][nt * 16 + l16] = f2bf(pr[nt][r]);
    }
    // Pl[wave] is wave-private; per-wave DS ordering -> no barrier needed
    bfrag pa0 = *(const bfrag*)&Pl[wave][l16][quad * 8];
    bfrag pa1 = *(const bfrag*)&Pl[wave][l16][32 + quad * 8];
#pragma unroll
    for (int dt = 0; dt < 4; dt++) {
      bfrag v0 = *(const bfrag*)&Vt[dt * 16 + l16][quad * 8];
      bfrag v1 = *(const bfrag*)&Vt[dt * 16 + l16][32 + quad * 8];
      o[dt] = __builtin_amdgcn_mfma_f32_16x16x32_bf16(pa0, v0, o[dt], 0, 0, 0);
      o[dt] = __builtin_amdgcn_mfma_f32_16x16x32_bf16(pa1, v1, o[dt], 0, 0, 0);
    }
  }
#pragma unroll
  for (int r = 0; r < 4; r++) {
#pragma unroll
    for (int off = 1; off < 16; off <<= 1) l_i[r] += __shfl_xor(l_i[r], off, 64);
    l_i[r] = 1.0f / fmaxf(l_i[r], 1e-30f);
  }
#pragma unroll
  for (int dt = 0; dt < 4; dt++) {
#pragma unroll
    for (int r = 0; r < 4; r++) {
      size_t qrow = rowbase + q0 + wave * 16 + quad * 4 + r;
      ctx[qrow * 512 + h * 64 + dt * 16 + l16] = f2bf(o[dt][r] * l_i[r]);
    }
  }
}

extern "C" void kernel_launch(void* const* d_in, const int* in_sizes, int n_in,
                              void* d_out, int out_size, void* d_ws, size_t ws_size,
                              hipStream_t stream) {
  const unsigned short* x = (const unsigned short*)d_in[0];
  const int* mask         = (const int*)d_in[1];
  const void* wq = d_in[2];  const void* bq = d_in[3];
  const void* wk = d_in[4];  const void* bk = d_in[5];
  const void* wv = d_in[6];  const void* bv = d_in[7];
  const void* wo = d_in[8];  const void* bo = d_in[9];
  const void* w1 = d_in[10]; const void* b1 = d_in[11];
  const void* w2 = d_in[12]; const void* b2 = d_in[13];
  const void* alpha1 = d_in[14]; const void* beta1 = d_in[15];
  const void* alpha2 = d_in[16]; const void* beta2 = d_in[17];

  char* ws = (char*)d_ws;
  int* flag            = (int*)(ws + 0);
  unsigned short* wqkvT= (unsigned short*)(ws + 65536);    // [1536][512]
  unsigned short* wqT  = wqkvT;
  unsigned short* wkT  = (unsigned short*)(ws + 589824);
  unsigned short* wvT  = (unsigned short*)(ws + 1114112);
  unsigned short* woT  = (unsigned short*)(ws + 1638400);
  unsigned short* w1T  = (unsigned short*)(ws + 2162688);  // [2048][512]
  unsigned short* w2T  = (unsigned short*)(ws + 4259840);  // [512][2048]
  float*          bcat = (float*)         (ws + 6356992);  // 4608 f32
  float*          x1   = (float*)         (ws + 6422528);  // [8192][512] f32
  unsigned short* n1   = (unsigned short*)(ws + 23199744); // also ctx, n2
  unsigned short* ctx  = n1;
  unsigned short* n2   = n1;
  unsigned short* qkb  = (unsigned short*)(ws + 31588352); // [8192][1536]
  unsigned short* vbt  = (unsigned short*)(ws + 56754176); // [2048][2048]
  unsigned short* ff1  = qkb;                              // [8192][2048] overlay

  dim3 blk(256);

  detect_k<<<1, blk, 0, stream>>>(x, flag);

  transpose_k<<<dim3(16, 16), blk, 0, stream>>>(wq, wqT, 512, 512, flag);
  transpose_k<<<dim3(16, 16), blk, 0, stream>>>(wk, wkT, 512, 512, flag);
  transpose_k<<<dim3(16, 16), blk, 0, stream>>>(wv, wvT, 512, 512, flag);
  transpose_k<<<dim3(16, 16), blk, 0, stream>>>(wo, woT, 512, 512, flag);
  transpose_k<<<dim3(64, 16), blk, 0, stream>>>(w1, w1T, 512, 2048, flag);
  transpose_k<<<dim3(16, 64), blk, 0, stream>>>(w2, w2T, 2048, 512, flag);
  bcat_k<<<18, blk, 0, stream>>>(bq, bk, bv, bo, b1, b2, bcat, flag);

  norm_k<0><<<2048, blk, 0, stream>>>(x, alpha1, beta1, n1, flag);
  // fused QKV: [8192][512] @ [1536][512]^T -> qkb
  gemm2_k<128, 0, 0, 0><<<dim3(64, 12), blk, 0, stream>>>(n1, wqkvT, bcat, nullptr, qkb, 1536, 512, flag);
  vtrans_k<<<dim3(64, 2, 32), blk, 0, stream>>>(qkb, vbt);
  attn_k<<<dim3(32, 32), blk, 0, stream>>>(qkb, vbt, mask, ctx);
  // out projection + residual(x) -> x1 f32  (N=512: 128x64 tile, 512 blocks)
  gemm2_k<64, 1, 1, 0><<<dim3(64, 8), blk, 0, stream>>>(ctx, woT, bcat + 1536, (const void*)x, x1, 512, 512, flag);
  norm_k<1><<<2048, blk, 0, stream>>>(x1, alpha2, beta2, n2, flag);
  // ffn1 + relu -> ff1
  gemm2_k<128, 0, 0, 1><<<dim3(64, 16), blk, 0, stream>>>(n2, w1T, bcat + 2048, nullptr, ff1, 2048, 512, flag);
  // ffn2 + residual(x1) -> d_out
  gemm2_k<64, 2, 2, 0><<<dim3(64, 8), blk, 0, stream>>>(ff1, w2T, bcat + 4096, x1, d_out, 512, 2048, flag);
}

// Round 6
// 324.465 us; speedup vs baseline: 1.3797x; 1.0517x over previous
//
#include <hip/hip_runtime.h>

typedef __bf16 bfrag __attribute__((ext_vector_type(8)));
typedef float f32x4 __attribute__((ext_vector_type(4)));
typedef unsigned short us8 __attribute__((ext_vector_type(8)));

__device__ __forceinline__ float bf2f(unsigned short s) {
  unsigned u = ((unsigned)s) << 16;
  float f;
  __builtin_memcpy(&f, &u, 4);
  return f;
}
__device__ __forceinline__ unsigned short f2bf(float f) {
  unsigned u;
  __builtin_memcpy(&u, &f, 4);
  u += 0x7fffu + ((u >> 16) & 1u);
  return (unsigned short)(u >> 16);
}
__device__ __forceinline__ float rdf(const void* p, size_t i, int isf) {
  return isf ? ((const float*)p)[i] : bf2f(((const unsigned short*)p)[i]);
}
// async global->LDS, 16B per lane; LDS dest = wave-uniform base + lane*16
__device__ __forceinline__ void gld16(const unsigned short* g, unsigned short* l) {
  __builtin_amdgcn_global_load_lds(
      (const __attribute__((address_space(1))) unsigned int*)g,
      (__attribute__((address_space(3))) unsigned int*)l, 16, 0, 0);
}

// ---------------- input dtype detector ---------------------------------
__global__ __launch_bounds__(256) void detect_k(
    const unsigned short* __restrict__ x, int* __restrict__ flag) {
  __shared__ int cnt;
  if (threadIdx.x == 0) cnt = 0;
  __syncthreads();
  int c = 0;
  for (int i = threadIdx.x; i < 4096; i += 256) {
    unsigned short s = x[2 * i];
    int e = (s >> 7) & 0xFF;
    if (e > 0xC2 || (e != 0 && e < 0x3D)) c++;
  }
  atomicAdd(&cnt, c);
  __syncthreads();
  if (threadIdx.x == 0) flag[0] = (cnt > 256) ? 1 : 0;
}

// ---------------- fused prep: 6 weight transposes + bias concat ---------
// grid 3090 blocks: [0,256)wq [256,512)wk [512,768)wv [768,1024)wo
// [1024,2048)w1 [2048,3072)w2 [3072,3090)bcat
__global__ __launch_bounds__(256) void prep_k(
    const void* wq, const void* wk, const void* wv, const void* wo,
    const void* w1, const void* w2,
    unsigned short* wqT, unsigned short* wkT, unsigned short* wvT,
    unsigned short* woT, unsigned short* w1T, unsigned short* w2T,
    const void* bq, const void* bk, const void* bv, const void* bo,
    const void* b1, const void* b2, float* __restrict__ bcat,
    const int* __restrict__ flag) {
  __shared__ unsigned short tile[32][33];
  int isf = flag[0];
  int bid = blockIdx.x;
  int tid = threadIdx.x;
  if (bid >= 3072) {
    int i = (bid - 3072) * 256 + tid;
    if (i >= 4608) return;
    float v;
    if (i < 512) v = rdf(bq, i, isf);
    else if (i < 1024) v = rdf(bk, i - 512, isf);
    else if (i < 1536) v = rdf(bv, i - 1024, isf);
    else if (i < 2048) v = rdf(bo, i - 1536, isf);
    else if (i < 4096) v = rdf(b1, i - 2048, isf);
    else v = rdf(b2, i - 4096, isf);
    bcat[i] = v;
    return;
  }
  const void* W;
  unsigned short* Wt;
  int K, N, t;
  if (bid < 1024) {
    K = 512; N = 512; t = bid & 255;
    if (bid < 256) { W = wq; Wt = wqT; }
    else if (bid < 512) { W = wk; Wt = wkT; }
    else if (bid < 768) { W = wv; Wt = wvT; }
    else { W = wo; Wt = woT; }
  } else if (bid < 2048) {
    W = w1; Wt = w1T; K = 512; N = 2048; t = bid - 1024;
  } else {
    W = w2; Wt = w2T; K = 2048; N = 512; t = bid - 2048;
  }
  int nx = N >> 5;
  int n0 = (t % nx) * 32, k0 = (t / nx) * 32;
#pragma unroll
  for (int i = 0; i < 4; i++) {
    int e = tid + i * 256;
    int r = e >> 5, c = e & 31;
    tile[r][c] = f2bf(rdf(W, (size_t)(k0 + r) * N + n0 + c, isf));
  }
  __syncthreads();
#pragma unroll
  for (int i = 0; i < 4; i++) {
    int e = tid + i * 256;
    int r = e >> 5, c = e & 31;
    Wt[(size_t)(n0 + r) * K + k0 + c] = tile[c][r];
  }
}

// ---------------- V transpose: qkb v-cols -> vbt[bh][d][s] --------------
__global__ __launch_bounds__(256) void vtrans_k(
    const unsigned short* __restrict__ qkb, unsigned short* __restrict__ vbt) {
  __shared__ unsigned short tile[32][33];
  int tid = threadIdx.x;
  int s0 = blockIdx.x * 32;
  int d0 = blockIdx.y * 32;
  int bh = blockIdx.z, b = bh >> 3, h = bh & 7;
#pragma unroll
  for (int i = 0; i < 4; i++) {
    int e = tid + i * 256;
    int r = e >> 5, c = e & 31;
    tile[r][c] = qkb[((size_t)b * 2048 + s0 + r) * 1536 + 1024 + h * 64 + d0 + c];
  }
  __syncthreads();
#pragma unroll
  for (int i = 0; i < 4; i++) {
    int e = tid + i * 256;
    int r = e >> 5, c = e & 31;
    vbt[((size_t)bh * 64 + d0 + r) * 2048 + s0 + c] = tile[c][r];
  }
}

// ---------------- layernorm (ddof=1 std, eps on std) --------------------
template <int XMODE>
__global__ __launch_bounds__(256) void norm_k(
    const void* __restrict__ xin, const void* __restrict__ alpha,
    const void* __restrict__ beta, unsigned short* __restrict__ out,
    const int* __restrict__ flag) {
  constexpr int E = 512;
  int isf = flag[0];
  int xf = XMODE ? 1 : isf;
  int tid = threadIdx.x;
  int wave = tid >> 6, lane = tid & 63;
  size_t tok = (size_t)blockIdx.x * 4 + wave;
  float v[8];
  if (xf) {
    const float* xp = (const float*)xin + tok * E + lane * 8;
    float4 a0 = *(const float4*)xp;
    float4 a1 = *(const float4*)(xp + 4);
    v[0] = a0.x; v[1] = a0.y; v[2] = a0.z; v[3] = a0.w;
    v[4] = a1.x; v[5] = a1.y; v[6] = a1.z; v[7] = a1.w;
  } else {
    us8 u = *(const us8*)((const unsigned short*)xin + tok * E + lane * 8);
#pragma unroll
    for (int j = 0; j < 8; j++) v[j] = bf2f(u[j]);
  }
  float s = 0.f, sq = 0.f;
#pragma unroll
  for (int j = 0; j < 8; j++) { s += v[j]; sq += v[j] * v[j]; }
#pragma unroll
  for (int off = 1; off < 64; off <<= 1) {
    s += __shfl_xor(s, off, 64);
    sq += __shfl_xor(sq, off, 64);
  }
  float mean = s * (1.0f / 512.0f);
  float var = fmaxf((sq - 512.0f * mean * mean) * (1.0f / 511.0f), 0.0f);
  float inv = rdf(alpha, 0, isf) / (sqrtf(var) + 1e-6f);
  float be = rdf(beta, 0, isf);
  us8 ov;
#pragma unroll
  for (int j = 0; j < 8; j++) ov[j] = f2bf((v[j] - mean) * inv + be);
  *(us8*)((unsigned short*)out + tok * E + lane * 8) = ov;
}

// ---------------- GEMM m97-style: 128xTN tile, BK=32, global_load_lds ----
template <int TN, int RES, int OUTM, int RELU>
__global__ __launch_bounds__(256) void gemm2_k(
    const unsigned short* __restrict__ A,
    const unsigned short* __restrict__ Bt,
    const float* __restrict__ bias,
    const void* __restrict__ res,
    void* __restrict__ outp,
    int N, int K, const int* __restrict__ flag) {
  constexpr int MT = (TN == 128) ? 4 : 2;
  __shared__ alignas(16) unsigned short As[128 * 32];
  __shared__ alignas(16) unsigned short Bs[TN * 32];
  int isf = flag[0];
  int outf32 = (OUTM == 1) || (OUTM == 2 && isf);
  int tid = threadIdx.x;
  int wave = tid >> 6, lane = tid & 63;
  int quad = lane >> 4, l16 = lane & 15;
  int wm = (TN == 128) ? (wave >> 1) : wave;
  int wn = (TN == 128) ? (wave & 1) : 0;
  size_t m0 = (size_t)blockIdx.x * 128;
  size_t n0 = (size_t)blockIdx.y * TN;

  int lrow = lane >> 2;
  int kseg = (lane & 3) * 8;

  const unsigned short* ag = A + (m0 + wave * 16 + lrow) * K + kseg;
  const unsigned short* bg = Bt + (n0 + wave * 16 + lrow) * K + kseg;
  unsigned short* asl = &As[(wave * 16) * 32];
  unsigned short* bsl = &Bs[(wave * 16) * 32];

  f32x4 acc[MT][4];
#pragma unroll
  for (int i = 0; i < MT; i++)
#pragma unroll
    for (int j = 0; j < 4; j++) acc[i][j] = {0.f, 0.f, 0.f, 0.f};

  for (int k0 = 0; k0 < K; k0 += 32) {
    __syncthreads();
    gld16(ag + k0, asl);
    gld16(ag + (size_t)64 * K + k0, asl + 64 * 32);
    gld16(bg + k0, bsl);
    if (TN == 128) gld16(bg + (size_t)64 * K + k0, bsl + 64 * 32);
    __syncthreads();
    bfrag af[MT], bf[4];
#pragma unroll
    for (int i = 0; i < MT; i++)
      af[i] = *(const bfrag*)&As[(wm * (MT * 16) + i * 16 + l16) * 32 + quad * 8];
#pragma unroll
    for (int j = 0; j < 4; j++)
      bf[j] = *(const bfrag*)&Bs[(wn * 64 + j * 16 + l16) * 32 + quad * 8];
#pragma unroll
    for (int i = 0; i < MT; i++)
#pragma unroll
      for (int j = 0; j < 4; j++)
        acc[i][j] = __builtin_amdgcn_mfma_f32_16x16x32_bf16(af[i], bf[j], acc[i][j], 0, 0, 0);
  }
#pragma unroll
  for (int j = 0; j < 4; j++) {
    size_t n = n0 + wn * 64 + j * 16 + l16;
    float bv = bias[n];
#pragma unroll
    for (int i = 0; i < MT; i++) {
#pragma unroll
      for (int r = 0; r < 4; r++) {
        size_t m = m0 + wm * (MT * 16) + i * 16 + quad * 4 + r;
        float vv = acc[i][j][r] + bv;
        if (RELU) vv = fmaxf(vv, 0.0f);
        if (RES == 1) vv += rdf(res, m * N + n, isf);
        else if (RES == 2) vv += ((const float*)res)[m * N + n];
        if (outf32) ((float*)outp)[m * N + n] = vv;
        else ((unsigned short*)outp)[m * N + n] = f2bf(vv);
      }
    }
  }
}

// ---------------- flash attention (max-free softmax, lean VALU) ---------
__global__ __launch_bounds__(256) void attn_k(
    const unsigned short* __restrict__ qkb,  // [8192][1536] q|k|v
    const unsigned short* __restrict__ vbt,  // [32*64][2048] = V^T per bh
    const int* __restrict__ mask,
    unsigned short* __restrict__ ctx) {      // [8192][512]
  constexpr int S = 2048;
  __shared__ alignas(16) unsigned short Kt[64][72];
  __shared__ alignas(16) unsigned short Vt[64][72];  // [d][key]
  __shared__ alignas(16) unsigned short Pl[4][16][68];
  __shared__ float mskf[64];
  int tid = threadIdx.x, wave = tid >> 6, lane = tid & 63;
  int quad = lane >> 4, l16 = lane & 15;
  int q0 = blockIdx.x * 64;
  int bh = blockIdx.y, b = bh >> 3, h = bh & 7;
  size_t rowbase = (size_t)b * S;

  bfrag qf0, qf1;
  {
    const unsigned short* qp =
        qkb + (rowbase + q0 + wave * 16 + l16) * 1536 + h * 64 + quad * 8;
    qf0 = *(const bfrag*)qp;
    qf1 = *(const bfrag*)(qp + 32);
  }
  f32x4 o[4] = {{0, 0, 0, 0}, {0, 0, 0, 0}, {0, 0, 0, 0}, {0, 0, 0, 0}};
  float l_i[4] = {0.f, 0.f, 0.f, 0.f};

  int srow = tid >> 2;
  int c0 = (tid & 3) * 8;
  const unsigned short* kbase = qkb + 512 + h * 64;
  const unsigned short* vrow = vbt + ((size_t)bh * 64 + srow) * S;
  const float SC = 0.18033688f;  // 0.125 * log2(e); exp(s/8) == exp2(s*SC)

  for (int kt = 0; kt < S; kt += 64) {
    __syncthreads();
    {
      const unsigned short* kp = kbase + (rowbase + kt + srow) * 1536;
      *(uint4*)&Kt[srow][c0]      = *(const uint4*)(kp + c0);
      *(uint4*)&Kt[srow][c0 + 32] = *(const uint4*)(kp + c0 + 32);
      *(uint4*)&Vt[srow][c0]      = *(const uint4*)(vrow + kt + c0);
      *(uint4*)&Vt[srow][c0 + 32] = *(const uint4*)(vrow + kt + c0 + 32);
    }
    if (tid < 64) mskf[tid] = mask[rowbase + kt + tid] ? 0.0f : -1e5f;
    __syncthreads();

    float pr[4][4];
#pragma unroll
    for (int nt = 0; nt < 4; nt++) {
      f32x4 s = {0, 0, 0, 0};
      bfrag k0f = *(const bfrag*)&Kt[nt * 16 + l16][quad * 8];
      bfrag k1f = *(const bfrag*)&Kt[nt * 16 + l16][32 + quad * 8];
      s = __builtin_amdgcn_mfma_f32_16x16x32_bf16(qf0, k0f, s, 0, 0, 0);
      s = __builtin_amdgcn_mfma_f32_16x16x32_bf16(qf1, k1f, s, 0, 0, 0);
      float mb = mskf[nt * 16 + l16];
#pragma unroll
      for (int r = 0; r < 4; r++) {
        // exp(score/8 + maskbias) via one fma + one v_exp; masked -> exact 0
        float p = __builtin_amdgcn_exp2f(fminf(fmaf(s[r], SC, mb), 50.0f));
        pr[nt][r] = p;
        unsigned u;
        __builtin_memcpy(&u, &p, 4);
        Pl[wave][quad * 4 + r][nt * 16 + l16] = (unsigned short)(u >> 16);
      }
    }
#pragma unroll
    for (int r = 0; r < 4; r++)
      l_i[r] += (pr[0][r] + pr[1][r]) + (pr[2][r] + pr[3][r]);
    // Pl[wave] is wave-private; per-wave DS ordering -> no barrier needed
    bfrag pa0 = *(const bfrag*)&Pl[wave][l16][quad * 8];
    bfrag pa1 = *(const bfrag*)&Pl[wave][l16][32 + quad * 8];
#pragma unroll
    for (int dt = 0; dt < 4; dt++) {
      bfrag v0 = *(const bfrag*)&Vt[dt * 16 + l16][quad * 8];
      bfrag v1 = *(const bfrag*)&Vt[dt * 16 + l16][32 + quad * 8];
      o[dt] = __builtin_amdgcn_mfma_f32_16x16x32_bf16(pa0, v0, o[dt], 0, 0, 0);
      o[dt] = __builtin_amdgcn_mfma_f32_16x16x32_bf16(pa1, v1, o[dt], 0, 0, 0);
    }
  }
#pragma unroll
  for (int r = 0; r < 4; r++) {
#pragma unroll
    for (int off = 1; off < 16; off <<= 1) l_i[r] += __shfl_xor(l_i[r], off, 64);
    l_i[r] = 1.0f / fmaxf(l_i[r], 1e-30f);
  }
#pragma unroll
  for (int dt = 0; dt < 4; dt++) {
#pragma unroll
    for (int r = 0; r < 4; r++) {
      size_t qrow = rowbase + q0 + wave * 16 + quad * 4 + r;
      ctx[qrow * 512 + h * 64 + dt * 16 + l16] = f2bf(o[dt][r] * l_i[r]);
    }
  }
}

extern "C" void kernel_launch(void* const* d_in, const int* in_sizes, int n_in,
                              void* d_out, int out_size, void* d_ws, size_t ws_size,
                              hipStream_t stream) {
  const unsigned short* x = (const unsigned short*)d_in[0];
  const int* mask         = (const int*)d_in[1];
  const void* wq = d_in[2];  const void* bq = d_in[3];
  const void* wk = d_in[4];  const void* bk = d_in[5];
  const void* wv = d_in[6];  const void* bv = d_in[7];
  const void* wo = d_in[8];  const void* bo = d_in[9];
  const void* w1 = d_in[10]; const void* b1 = d_in[11];
  const void* w2 = d_in[12]; const void* b2 = d_in[13];
  const void* alpha1 = d_in[14]; const void* beta1 = d_in[15];
  const void* alpha2 = d_in[16]; const void* beta2 = d_in[17];

  char* ws = (char*)d_ws;
  int* flag            = (int*)(ws + 0);
  unsigned short* wqkvT= (unsigned short*)(ws + 65536);    // [1536][512]
  unsigned short* wqT  = wqkvT;
  unsigned short* wkT  = (unsigned short*)(ws + 589824);
  unsigned short* wvT  = (unsigned short*)(ws + 1114112);
  unsigned short* woT  = (unsigned short*)(ws + 1638400);
  unsigned short* w1T  = (unsigned short*)(ws + 2162688);  // [2048][512]
  unsigned short* w2T  = (unsigned short*)(ws + 4259840);  // [512][2048]
  float*          bcat = (float*)         (ws + 6356992);  // 4608 f32
  float*          x1   = (float*)         (ws + 6422528);  // [8192][512] f32
  unsigned short* n1   = (unsigned short*)(ws + 23199744); // also ctx, n2
  unsigned short* ctx  = n1;
  unsigned short* n2   = n1;
  unsigned short* qkb  = (unsigned short*)(ws + 31588352); // [8192][1536]
  unsigned short* vbt  = (unsigned short*)(ws + 56754176); // [2048][2048]
  unsigned short* ff1  = qkb;                              // [8192][2048] overlay

  dim3 blk(256);

  detect_k<<<1, blk, 0, stream>>>(x, flag);
  prep_k<<<3090, blk, 0, stream>>>(wq, wk, wv, wo, w1, w2,
                                   wqT, wkT, wvT, woT, w1T, w2T,
                                   bq, bk, bv, bo, b1, b2, bcat, flag);

  norm_k<0><<<2048, blk, 0, stream>>>(x, alpha1, beta1, n1, flag);
  // fused QKV: [8192][512] @ [1536][512]^T -> qkb
  gemm2_k<128, 0, 0, 0><<<dim3(64, 12), blk, 0, stream>>>(n1, wqkvT, bcat, nullptr, qkb, 1536, 512, flag);
  vtrans_k<<<dim3(64, 2, 32), blk, 0, stream>>>(qkb, vbt);
  attn_k<<<dim3(32, 32), blk, 0, stream>>>(qkb, vbt, mask, ctx);
  // out projection + residual(x) -> x1 f32
  gemm2_k<64, 1, 1, 0><<<dim3(64, 8), blk, 0, stream>>>(ctx, woT, bcat + 1536, (const void*)x, x1, 512, 512, flag);
  norm_k<1><<<2048, blk, 0, stream>>>(x1, alpha2, beta2, n2, flag);
  // ffn1 + relu -> ff1
  gemm2_k<128, 0, 0, 1><<<dim3(64, 16), blk, 0, stream>>>(n2, w1T, bcat + 2048, nullptr, ff1, 2048, 512, flag);
  // ffn2 + residual(x1) -> d_out
  gemm2_k<64, 2, 2, 0><<<dim3(64, 8), blk, 0, stream>>>(ff1, w2T, bcat + 4096, x1, d_out, 512, 2048, flag);
}